// Round 13
// baseline (270.343 us; speedup 1.0000x reference)
//
#include <hip/hip_runtime.h>
#include <hip/hip_bf16.h>

#define NROWS 8192      // B*T
#define KDIM  768       // F_IN
#define VSZ   320       // V
#define GSZ   2         // G
#define NCOL  640       // G*V
#define DSZ   128       // D
#define BM    64        // rows per block
#define NMT   (NROWS / BM)             // 128 M-tiles
#define NBLK  (NMT * 2)                // 256 blocks (x2 group-halves) = 1/CU
#define NKB   24                       // K blocks of 32 (prep layout)
#define XQ_TOTAL (NROWS * GSZ * DSZ)   // 2097152
#define MARGIN 1.5f
#define XBLKS 3072                     // prep blocks for x
#define WBLKS 240                      // prep blocks for W

typedef __attribute__((ext_vector_type(8))) short bf16x8;
typedef __attribute__((ext_vector_type(4))) float f32x4;

static __device__ __forceinline__ short f2bf(float f) {
    union { __hip_bfloat16 h; short s; } u;
    u.h = __float2bfloat16(f);   // round-to-nearest-even
    return u.s;
}

static __device__ __forceinline__ void gload_lds16(const void* g, void* l) {
    __builtin_amdgcn_global_load_lds(
        (const __attribute__((address_space(1))) void*)g,
        (__attribute__((address_space(3))) void*)l, 16, 0, 0);
}

// ---------------- prep: pack x and W to frag-major bf16; zero accf ----------------
__global__ __launch_bounds__(256) void prep_k(const float* __restrict__ x,
                                              const float* __restrict__ W,
                                              short* __restrict__ Xb,
                                              short* __restrict__ Wb,
                                              float* __restrict__ accf) {
    const int bid = blockIdx.x;
    if (bid == 0) {
        for (int i = threadIdx.x; i < 2 * NCOL; i += 256) accf[i] = 0.f;
    }
    const float* src;
    short* dst;
    int id, row, k;
    if (bid < XBLKS) {
        id = bid * 256 + threadIdx.x;           // 0..786431
        const int lane = id & 63;
        const int f    = id >> 6;               // 0..12287
        const int rblk = f / NKB;
        const int kb   = f - rblk * NKB;
        row = rblk * 16 + (lane & 15);
        k   = kb * 32 + (lane >> 4) * 8;
        src = x; dst = Xb;
    } else {
        id = (bid - XBLKS) * 256 + threadIdx.x; // 0..61439
        const int lane = id & 63;
        const int f    = id >> 6;               // 0..959
        const int n    = f % 5;
        const int t2   = f / 5;
        const int hc   = t2 & 7;
        const int kb   = t2 >> 3;               // 0..23
        row = (hc * 5 + n) * 16 + (lane & 15);  // W col
        k   = kb * 32 + (lane >> 4) * 8;
        src = W; dst = Wb;
    }
    const float4 a = *(const float4*)(src + (size_t)row * KDIM + k);
    const float4 c = *(const float4*)(src + (size_t)row * KDIM + k + 4);
    bf16x8 r;
    r[0] = f2bf(a.x); r[1] = f2bf(a.y); r[2] = f2bf(a.z); r[3] = f2bf(a.w);
    r[4] = f2bf(c.x); r[5] = f2bf(c.y); r[6] = f2bf(c.z); r[7] = f2bf(c.w);
    *(bf16x8*)(dst + (size_t)id * 8) = r;
}

#define STAGE(kb64, BUF) do {                                                  \
    _Pragma("unroll")                                                          \
    for (int j = 0; j < 3; ++j) {                                              \
        const int f = w + 16 * j;                                              \
        const short* src;                                                      \
        if (f < 8) {                                                           \
            src = Xb + ((size_t)(mt * 4 + (f >> 1)) * 24 + (2 * (kb64) + (f & 1))) * 512; \
        } else {                                                               \
            const int i = f - 8;                                               \
            const int kf = i / 20, rm = i % 20;                                \
            src = Wb + ((size_t)((2 * (kb64) + kf) * 8 + hc0 + rm / 5) * 5 + rm % 5) * 512; \
        }                                                                      \
        gload_lds16(src + lane * 8, (char*)(BUF) + f * 1024);                  \
    }                                                                          \
} while (0)

#define COMPUTE(BUF) do {                                                      \
    const char* _bp = (const char*)(BUF);                                      \
    const bf16x8 a0 = *(const bf16x8*)(_bp + (rs * 2 + 0) * 1024 + lane * 16); \
    const bf16x8 a1 = *(const bf16x8*)(_bp + (rs * 2 + 1) * 1024 + lane * 16); \
    bf16x8 b0_[5], b1_[5];                                                     \
    _Pragma("unroll")                                                          \
    for (int n = 0; n < 5; ++n) {                                              \
        b0_[n] = *(const bf16x8*)(_bp + 8192 + (cc * 5 + n) * 1024 + lane * 16);      \
        b1_[n] = *(const bf16x8*)(_bp + 8192 + (20 + cc * 5 + n) * 1024 + lane * 16); \
    }                                                                          \
    _Pragma("unroll")                                                          \
    for (int n = 0; n < 5; ++n)                                                \
        acc[n] = __builtin_amdgcn_mfma_f32_16x16x32_bf16(a0, b0_[n], acc[n], 0, 0, 0); \
    _Pragma("unroll")                                                          \
    for (int n = 0; n < 5; ++n)                                                \
        acc[n] = __builtin_amdgcn_mfma_f32_16x16x32_bf16(a1, b1_[n], acc[n], 0, 0, 0); \
} while (0)

#define SYNCN do {                                                             \
    asm volatile("s_waitcnt vmcnt(3)" ::: "memory");                           \
    __builtin_amdgcn_sched_barrier(0);                                         \
    __builtin_amdgcn_s_barrier();                                              \
} while (0)
#define SYNC0 do {                                                             \
    asm volatile("s_waitcnt vmcnt(0)" ::: "memory");                           \
    __builtin_amdgcn_sched_barrier(0);                                         \
    __builtin_amdgcn_s_barrier();                                              \
} while (0)

// ---------------- production fused kernel (identical to round 12) ----------------
__global__ __launch_bounds__(1024, 4) void fused_vq_k(
    const short* __restrict__ Xb, const short* __restrict__ Wb,
    const float* __restrict__ x, const float* __restrict__ W,
    const float* __restrict__ b, const float* __restrict__ codebook,
    float* __restrict__ accf, float* __restrict__ xq) {

    __shared__ __align__(16) char bufs[3][48 * 1024];   // 147,456 B
    __shared__ float pacc[4][VSZ];
    __shared__ float cnt_f[VSZ];
    __shared__ float wmax[BM][4];
    __shared__ int   warg[BM][4];
    __shared__ float ssum[BM][4];
    __shared__ float rmax_s[BM];
    __shared__ int   rarg_s[BM];
    __shared__ int   cnt_s[BM];
    __shared__ int   list_s[BM][16];
    __shared__ int   code_s[BM];
    __shared__ int   work_s[BM];
    __shared__ int   nwork_s;

    const int tid   = threadIdx.x;
    const int lane  = tid & 63;
    const int w     = tid >> 6;
    const int l15   = lane & 15;
    const int l4    = lane >> 4;
    const int sb    = ((int)blockIdx.x & 7) * (NBLK / 8) + ((int)blockIdx.x >> 3);
    const int mt    = sb >> 1;
    const int h     = sb & 1;
    const int row0  = mt * BM;
    const int rs    = w >> 2;
    const int cc    = w & 3;
    const int rbase = rs * 16;
    const int hc0   = h * 4;
    const int nf0   = h * 20 + cc * 5;

    for (int i = tid; i < VSZ; i += 1024) cnt_f[i] = 0.f;
    if (tid < BM) cnt_s[tid] = 0;
    if (tid == 0) nwork_s = 0;

    char* B0 = bufs[0];
    char* B1 = bufs[1];
    char* B2 = bufs[2];

    f32x4 acc[5];
#pragma unroll
    for (int n = 0; n < 5; ++n) acc[n] = (f32x4){0.f, 0.f, 0.f, 0.f};

    STAGE(0, B0);
    STAGE(1, B1);
    __syncthreads();

#pragma unroll 1
    for (int t = 0; t < 3; ++t) {
        const int kb = 3 * t;
        STAGE(kb + 2, B2); COMPUTE(B0); SYNCN;
        STAGE(kb + 3, B0); COMPUTE(B1); SYNCN;
        STAGE(kb + 4, B1); COMPUTE(B2); SYNCN;
    }
    STAGE(11, B2); COMPUTE(B0); SYNCN;
    COMPUTE(B1); SYNC0;
    COMPUTE(B2);

#pragma unroll
    for (int n = 0; n < 5; ++n) {
        const float bv = b[(nf0 + n) * 16 + l15];
#pragma unroll
        for (int r = 0; r < 4; ++r) acc[n][r] += bv;
    }

    float m4[4]; int a4[4];
#pragma unroll
    for (int r = 0; r < 4; ++r) { m4[r] = -3.4e38f; a4[r] = 0x7fffffff; }
#pragma unroll
    for (int n = 0; n < 5; ++n) {
        const int col = (nf0 + n) * 16 + l15;
#pragma unroll
        for (int r = 0; r < 4; ++r) {
            const float v = acc[n][r];
            if (v > m4[r]) { m4[r] = v; a4[r] = col; }
        }
    }
#pragma unroll
    for (int off = 8; off >= 1; off >>= 1)
#pragma unroll
        for (int r = 0; r < 4; ++r) {
            const float om = __shfl_xor(m4[r], off);
            const int   oa = __shfl_xor(a4[r], off);
            if (om > m4[r] || (om == m4[r] && oa < a4[r])) { m4[r] = om; a4[r] = oa; }
        }
    if (l15 == 0)
#pragma unroll
        for (int r = 0; r < 4; ++r) {
            const int row = rbase + l4 * 4 + r;
            wmax[row][cc] = m4[r];
            warg[row][cc] = a4[r];
        }
    __syncthreads();

    if (tid < BM) {
        float m = -3.4e38f; int c = 0x7fffffff;
#pragma unroll
        for (int q = 0; q < 4; ++q) {
            const float mq = wmax[tid][q];
            const int   cq = warg[tid][q];
            if (mq > m || (mq == m && cq < c)) { m = mq; c = cq; }
        }
        rmax_s[tid] = m;
        rarg_s[tid] = c;
    }
    __syncthreads();

    float rm[4];
#pragma unroll
    for (int r = 0; r < 4; ++r) rm[r] = rmax_s[rbase + l4 * 4 + r];
    float sden[4] = {0.f, 0.f, 0.f, 0.f};
#pragma unroll
    for (int n = 0; n < 5; ++n) {
        const int col = (nf0 + n) * 16 + l15;
#pragma unroll
        for (int r = 0; r < 4; ++r) {
            const float v = acc[n][r];
            if (v > rm[r] - MARGIN) {
                const int row = rbase + l4 * 4 + r;
                const int idx = atomicAdd(&cnt_s[row], 1);
                if (idx < 16) list_s[row][idx] = col;
            }
            const float e = __expf(v - rm[r]);
            acc[n][r] = e;
            sden[r] += e;
        }
    }
#pragma unroll
    for (int off = 8; off >= 1; off >>= 1)
#pragma unroll
        for (int r = 0; r < 4; ++r) sden[r] += __shfl_xor(sden[r], off);
    if (l15 == 0)
#pragma unroll
        for (int r = 0; r < 4; ++r) ssum[rbase + l4 * 4 + r][cc] = sden[r];
    __syncthreads();

    if (tid < BM) {
        if (cnt_s[tid] <= 1) {
            code_s[tid] = rarg_s[tid];
        } else {
            const int wi = atomicAdd(&nwork_s, 1);
            work_s[wi] = tid;
        }
    }

    float inv[4];
#pragma unroll
    for (int r = 0; r < 4; ++r) {
        const int row = rbase + l4 * 4 + r;
        inv[r] = 1.f / (ssum[row][0] + ssum[row][1] + ssum[row][2] + ssum[row][3]);
    }
#pragma unroll
    for (int n = 0; n < 5; ++n) {
        float pc = 0.f;
#pragma unroll
        for (int r = 0; r < 4; ++r) pc += acc[n][r] * inv[r];
        pc += __shfl_xor(pc, 16);
        pc += __shfl_xor(pc, 32);
        if (l4 == 0) pacc[rs][(nf0 + n) * 16 + l15 - h * VSZ] = pc;
    }
    __syncthreads();

    const int nwork = nwork_s;
    for (int it = w; it < nwork; it += 16) {
        const int row  = work_s[it];
        const int grow = row0 + row;
        const int nc   = min(cnt_s[row], 16);
        float bestv = -3.4e38f; int bestc = 0x7fffffff;
        for (int ci = 0; ci < nc; ++ci) {
            const int col = list_s[row][ci];
            float p = 0.f;
            for (int j = lane; j < KDIM; j += 64)
                p += x[(size_t)grow * KDIM + j] * W[(size_t)col * KDIM + j];
#pragma unroll
            for (int off = 32; off >= 1; off >>= 1) p += __shfl_xor(p, off);
            p += b[col];
            if (p > bestv || (p == bestv && col < bestc)) { bestv = p; bestc = col; }
        }
        if (lane == 0) code_s[row] = bestc;
    }
    __syncthreads();

    if (tid < BM) atomicAdd(&cnt_f[code_s[tid] - h * VSZ], 1.f);

#pragma unroll
    for (int u = 0; u < 2; ++u) {
        const int f   = tid + u * 1024;
        const int row = f >> 5;
        const int d4  = (f & 31) * 4;
        const int k   = code_s[row];
        const float4 v = *(const float4*)(codebook + (size_t)k * DSZ + d4);
        *(float4*)(xq + (size_t)(row0 + row) * (GSZ * DSZ) + h * DSZ + d4) = v;
    }
    __syncthreads();

    for (int i = tid; i < VSZ; i += 1024) {
        atomicAdd(&accf[h * VSZ + i], cnt_f[i]);
        atomicAdd(&accf[NCOL + h * VSZ + i],
                  pacc[0][i] + pacc[1][i] + pacc[2][i] + pacc[3][i]);
    }
}

// ---------------- perplexities + constant ----------------
__global__ __launch_bounds__(640) void finalize_k(const float* __restrict__ accf,
                                                  float* __restrict__ out_scalars) {
    __shared__ float se_c[GSZ], se_p[GSZ];
    const int t = threadIdx.x;
    if (t < GSZ) { se_c[t] = 0.f; se_p[t] = 0.f; }
    __syncthreads();
    const int g = t / VSZ;
    const float hp = accf[t]        * (1.f / (float)NROWS);
    const float ap = accf[NCOL + t] * (1.f / (float)NROWS);
    float tc = hp * logf(hp + 1e-7f);
    float tp = ap * logf(ap + 1e-7f);
#pragma unroll
    for (int off = 32; off >= 1; off >>= 1) {
        tc += __shfl_xor(tc, off);
        tp += __shfl_xor(tp, off);
    }
    if ((t & 63) == 0) { atomicAdd(&se_c[g], tc); atomicAdd(&se_p[g], tp); }
    __syncthreads();
    if (t == 0) {
        out_scalars[0] = (float)NCOL;
        out_scalars[1] = expf(-se_c[0]) + expf(-se_c[1]);
        out_scalars[2] = expf(-se_p[0]) + expf(-se_p[1]);
    }
}

// ================= DIAGNOSTIC (scratch-only, self-repeating to surface in top-5) =================
// REP repeats of the full block workload. EPI: run epilogue phases. REFINE: real fp32 refine.
template<int REP, bool EPI, bool REFINE>
__global__ __launch_bounds__(1024, 4) void diag_k(
    const short* __restrict__ Xb, const short* __restrict__ Wb,
    const float* __restrict__ x, const float* __restrict__ W,
    const float* __restrict__ b, const float* __restrict__ codebook,
    float* __restrict__ accf2, float* __restrict__ xq2, float* __restrict__ sink) {

    __shared__ __align__(16) char bufs[3][48 * 1024];
    __shared__ float pacc[4][VSZ];
    __shared__ float cnt_f[VSZ];
    __shared__ float wmax[BM][4];
    __shared__ int   warg[BM][4];
    __shared__ float ssum[BM][4];
    __shared__ float rmax_s[BM];
    __shared__ int   rarg_s[BM];
    __shared__ int   cnt_s[BM];
    __shared__ int   list_s[BM][16];
    __shared__ int   code_s[BM];
    __shared__ int   work_s[BM];
    __shared__ int   nwork_s;

    const int tid   = threadIdx.x;
    const int lane  = tid & 63;
    const int w     = tid >> 6;
    const int l15   = lane & 15;
    const int l4    = lane >> 4;
    const int sb    = ((int)blockIdx.x & 7) * (NBLK / 8) + ((int)blockIdx.x >> 3);
    const int mt    = sb >> 1;
    const int h     = sb & 1;
    const int row0  = mt * BM;
    const int rs    = w >> 2;
    const int cc    = w & 3;
    const int rbase = rs * 16;
    const int hc0   = h * 4;
    const int nf0   = h * 20 + cc * 5;

    char* B0 = bufs[0];
    char* B1 = bufs[1];
    char* B2 = bufs[2];

    float keep = 0.f;

#pragma unroll 1
    for (int rep = 0; rep < REP; ++rep) {
        for (int i = tid; i < VSZ; i += 1024) cnt_f[i] = 0.f;
        if (tid < BM) cnt_s[tid] = 0;
        if (tid == 0) nwork_s = 0;

        f32x4 acc[5];
#pragma unroll
        for (int n = 0; n < 5; ++n) acc[n] = (f32x4){0.f, 0.f, 0.f, 0.f};

        STAGE(0, B0);
        STAGE(1, B1);
        __syncthreads();

#pragma unroll 1
        for (int t = 0; t < 3; ++t) {
            const int kb = 3 * t;
            STAGE(kb + 2, B2); COMPUTE(B0); SYNCN;
            STAGE(kb + 3, B0); COMPUTE(B1); SYNCN;
            STAGE(kb + 4, B1); COMPUTE(B2); SYNCN;
        }
        STAGE(11, B2); COMPUTE(B0); SYNCN;
        COMPUTE(B1); SYNC0;
        COMPUTE(B2);

#pragma unroll
        for (int n = 0; n < 5; ++n) {
            const float bv = b[(nf0 + n) * 16 + l15];
#pragma unroll
            for (int r = 0; r < 4; ++r) acc[n][r] += bv;
        }

        if (!EPI) {
            float s = 0.f;
#pragma unroll
            for (int n = 0; n < 5; ++n)
#pragma unroll
                for (int r = 0; r < 4; ++r) s += acc[n][r];
            keep += s;
            __syncthreads();
            continue;
        }

        // ---- epilogue (same phases as production) ----
        float m4[4]; int a4[4];
#pragma unroll
        for (int r = 0; r < 4; ++r) { m4[r] = -3.4e38f; a4[r] = 0x7fffffff; }
#pragma unroll
        for (int n = 0; n < 5; ++n) {
            const int col = (nf0 + n) * 16 + l15;
#pragma unroll
            for (int r = 0; r < 4; ++r) {
                const float v = acc[n][r];
                if (v > m4[r]) { m4[r] = v; a4[r] = col; }
            }
        }
#pragma unroll
        for (int off = 8; off >= 1; off >>= 1)
#pragma unroll
            for (int r = 0; r < 4; ++r) {
                const float om = __shfl_xor(m4[r], off);
                const int   oa = __shfl_xor(a4[r], off);
                if (om > m4[r] || (om == m4[r] && oa < a4[r])) { m4[r] = om; a4[r] = oa; }
            }
        if (l15 == 0)
#pragma unroll
            for (int r = 0; r < 4; ++r) {
                const int row = rbase + l4 * 4 + r;
                wmax[row][cc] = m4[r];
                warg[row][cc] = a4[r];
            }
        __syncthreads();

        if (tid < BM) {
            float m = -3.4e38f; int c = 0x7fffffff;
#pragma unroll
            for (int q = 0; q < 4; ++q) {
                const float mq = wmax[tid][q];
                const int   cq = warg[tid][q];
                if (mq > m || (mq == m && cq < c)) { m = mq; c = cq; }
            }
            rmax_s[tid] = m;
            rarg_s[tid] = c;
        }
        __syncthreads();

        float rm[4];
#pragma unroll
        for (int r = 0; r < 4; ++r) rm[r] = rmax_s[rbase + l4 * 4 + r];
        float sden[4] = {0.f, 0.f, 0.f, 0.f};
#pragma unroll
        for (int n = 0; n < 5; ++n) {
            const int col = (nf0 + n) * 16 + l15;
#pragma unroll
            for (int r = 0; r < 4; ++r) {
                const float v = acc[n][r];
                if (v > rm[r] - MARGIN) {
                    const int row = rbase + l4 * 4 + r;
                    const int idx = atomicAdd(&cnt_s[row], 1);
                    if (idx < 16) list_s[row][idx] = col;
                }
                const float e = __expf(v - rm[r]);
                acc[n][r] = e;
                sden[r] += e;
            }
        }
#pragma unroll
        for (int off = 8; off >= 1; off >>= 1)
#pragma unroll
            for (int r = 0; r < 4; ++r) sden[r] += __shfl_xor(sden[r], off);
        if (l15 == 0)
#pragma unroll
            for (int r = 0; r < 4; ++r) ssum[rbase + l4 * 4 + r][cc] = sden[r];
        __syncthreads();

        if (tid < BM) {
            if (cnt_s[tid] <= 1) {
                code_s[tid] = rarg_s[tid];
            } else {
                const int wi = atomicAdd(&nwork_s, 1);
                work_s[wi] = tid;
            }
        }

        float inv[4];
#pragma unroll
        for (int r = 0; r < 4; ++r) {
            const int row = rbase + l4 * 4 + r;
            inv[r] = 1.f / (ssum[row][0] + ssum[row][1] + ssum[row][2] + ssum[row][3]);
        }
#pragma unroll
        for (int n = 0; n < 5; ++n) {
            float pc = 0.f;
#pragma unroll
            for (int r = 0; r < 4; ++r) pc += acc[n][r] * inv[r];
            pc += __shfl_xor(pc, 16);
            pc += __shfl_xor(pc, 32);
            if (l4 == 0) pacc[rs][(nf0 + n) * 16 + l15 - h * VSZ] = pc;
        }
        __syncthreads();

        const int nwork = nwork_s;
        if (REFINE) {
            for (int it = w; it < nwork; it += 16) {
                const int row  = work_s[it];
                const int grow = row0 + row;
                const int nc   = min(cnt_s[row], 16);
                float bestv = -3.4e38f; int bestc = 0x7fffffff;
                for (int ci = 0; ci < nc; ++ci) {
                    const int col = list_s[row][ci];
                    float p = 0.f;
                    for (int j = lane; j < KDIM; j += 64)
                        p += x[(size_t)grow * KDIM + j] * W[(size_t)col * KDIM + j];
#pragma unroll
                    for (int off = 32; off >= 1; off >>= 1) p += __shfl_xor(p, off);
                    p += b[col];
                    if (p > bestv || (p == bestv && col < bestc)) { bestv = p; bestc = col; }
                }
                if (lane == 0) code_s[row] = bestc;
            }
        } else {
            for (int it = w; it < nwork; it += 16) {
                const int row = work_s[it];
                if (lane == 0) code_s[row] = list_s[row][0];
            }
        }
        __syncthreads();

        if (tid < BM) atomicAdd(&cnt_f[code_s[tid] - h * VSZ], 1.f);

#pragma unroll
        for (int u = 0; u < 2; ++u) {
            const int f   = tid + u * 1024;
            const int row = f >> 5;
            const int d4  = (f & 31) * 4;
            const int k   = code_s[row];
            const float4 v = *(const float4*)(codebook + (size_t)k * DSZ + d4);
            *(float4*)(xq2 + (size_t)(row0 + row) * (GSZ * DSZ) + h * DSZ + d4) = v;
        }
        __syncthreads();

        for (int i = tid; i < VSZ; i += 1024) {
            atomicAdd(&accf2[h * VSZ + i], cnt_f[i]);
            atomicAdd(&accf2[NCOL + h * VSZ + i],
                      pacc[0][i] + pacc[1][i] + pacc[2][i] + pacc[3][i]);
        }
        __syncthreads();
    }

    if (!EPI) sink[(size_t)blockIdx.x * 1024 + tid] = keep;
}

extern "C" void kernel_launch(void* const* d_in, const int* in_sizes, int n_in,
                              void* d_out, int out_size, void* d_ws, size_t ws_size,
                              hipStream_t stream) {
    const float* x        = (const float*)d_in[0];
    const float* W        = (const float*)d_in[1];
    const float* b        = (const float*)d_in[2];
    const float* codebook = (const float*)d_in[3];
    float* out = (float*)d_out;

    char* ws = (char*)d_ws;
    short* Wb    = (short*)ws;                         //   983,040 B
    short* Xb    = (short*)(ws + 983040);              // 12,582,912 B  -> 13,565,952
    float* accf  = (float*)(ws + 13565952);            //     5,120 B  -> 13,571,072
    float* accf2 = (float*)(ws + 13571072);            //     5,120 B  -> 13,576,192
    float* sink  = (float*)(ws + 13576192);            // 1,048,576 B  -> 14,624,768
    float* xq2   = (float*)(ws + 14624768);            // 8,388,608 B  -> 23,013,376

    // ---- production path (identical to round 12) ----
    prep_k<<<dim3(XBLKS + WBLKS), dim3(256), 0, stream>>>(x, W, Xb, Wb, accf);
    fused_vq_k<<<dim3(NBLK), dim3(1024), 0, stream>>>(Xb, Wb, x, W, b, codebook,
                                                      accf, out);
    finalize_k<<<dim3(1), dim3(640), 0, stream>>>(accf, out + XQ_TOTAL);

    // ---- diagnostics (scratch-only) ----
    diag_k<5, false, false><<<dim3(NBLK), dim3(1024), 0, stream>>>(
        Xb, Wb, x, W, b, codebook, accf2, xq2, sink);          // GEMM-only x5
    diag_k<3, true, false><<<dim3(NBLK), dim3(1024), 0, stream>>>(
        Xb, Wb, x, W, b, codebook, accf2, xq2, sink);          // no-refine x3
    diag_k<2, true, true><<<dim3(NBLK), dim3(1024), 0, stream>>>(
        Xb, Wb, x, W, b, codebook, accf2, xq2, sink);          // full copy x2
}

// Round 14
// 56.369 us; speedup vs baseline: 4.7960x; 4.7960x over previous
//
#include <hip/hip_runtime.h>
#include <hip/hip_bf16.h>

#define NROWS 8192      // B*T
#define KDIM  768       // F_IN
#define VSZ   320       // V
#define GSZ   2         // G
#define NCOL  640       // G*V
#define DSZ   128       // D
#define BM    64        // rows per block
#define NMT   (NROWS / BM)             // 128 M-tiles
#define NBLK  (NMT * 2)                // 256 blocks (x2 group-halves) = 1/CU
#define NKB   24                       // K blocks of 32 (prep layout)
#define XQ_TOTAL (NROWS * GSZ * DSZ)   // 2097152
#define MARGIN 0.75f    // 12 sigma of bf16-dot pairwise error (sigma~0.062); was 1.5
#define XBLKS 3072                     // prep blocks for x
#define WBLKS 240                      // prep blocks for W

typedef __attribute__((ext_vector_type(8))) short bf16x8;
typedef __attribute__((ext_vector_type(4))) float f32x4;

static __device__ __forceinline__ short f2bf(float f) {
    union { __hip_bfloat16 h; short s; } u;
    u.h = __float2bfloat16(f);   // round-to-nearest-even
    return u.s;
}

static __device__ __forceinline__ void gload_lds16(const void* g, void* l) {
    __builtin_amdgcn_global_load_lds(
        (const __attribute__((address_space(1))) void*)g,
        (__attribute__((address_space(3))) void*)l, 16, 0, 0);
}

// ---------------- prep: pack x and W to frag-major bf16; zero accf ----------------
__global__ __launch_bounds__(256) void prep_k(const float* __restrict__ x,
                                              const float* __restrict__ W,
                                              short* __restrict__ Xb,
                                              short* __restrict__ Wb,
                                              float* __restrict__ accf) {
    const int bid = blockIdx.x;
    if (bid == 0) {
        for (int i = threadIdx.x; i < 2 * NCOL; i += 256) accf[i] = 0.f;
    }
    const float* src;
    short* dst;
    int id, row, k;
    if (bid < XBLKS) {
        id = bid * 256 + threadIdx.x;           // 0..786431
        const int lane = id & 63;
        const int f    = id >> 6;               // 0..12287
        const int rblk = f / NKB;
        const int kb   = f - rblk * NKB;
        row = rblk * 16 + (lane & 15);
        k   = kb * 32 + (lane >> 4) * 8;
        src = x; dst = Xb;
    } else {
        id = (bid - XBLKS) * 256 + threadIdx.x; // 0..61439
        const int lane = id & 63;
        const int f    = id >> 6;               // 0..959
        const int n    = f % 5;
        const int t2   = f / 5;
        const int hc   = t2 & 7;
        const int kb   = t2 >> 3;               // 0..23
        row = (hc * 5 + n) * 16 + (lane & 15);  // W col
        k   = kb * 32 + (lane >> 4) * 8;
        src = W; dst = Wb;
    }
    const float4 a = *(const float4*)(src + (size_t)row * KDIM + k);
    const float4 c = *(const float4*)(src + (size_t)row * KDIM + k + 4);
    bf16x8 r;
    r[0] = f2bf(a.x); r[1] = f2bf(a.y); r[2] = f2bf(a.z); r[3] = f2bf(a.w);
    r[4] = f2bf(c.x); r[5] = f2bf(c.y); r[6] = f2bf(c.z); r[7] = f2bf(c.w);
    *(bf16x8*)(dst + (size_t)id * 8) = r;
}

// Per K-step (64 k) stage: 48 frags = 8 A (f<8) + 40 B; wave w (of 8) issues
// f = w + 8j, j=0..5 (exactly 6 -> uniform vmcnt(6)). Frag f at byte f*1024.
// A frag f<8: row-chunk f>>1, k-half f&1.  B frag f>=8: i=f-8, kf=i/20, rm=i%20.
#define STAGE(kb64, BUF) do {                                                  \
    _Pragma("unroll")                                                          \
    for (int j = 0; j < 6; ++j) {                                              \
        const int f = w + 8 * j;                                               \
        const short* src;                                                      \
        if (f < 8) {                                                           \
            src = Xb + ((size_t)(mt * 4 + (f >> 1)) * 24 + (2 * (kb64) + (f & 1))) * 512; \
        } else {                                                               \
            const int i = f - 8;                                               \
            const int kf = i / 20, rm = i % 20;                                \
            src = Wb + ((size_t)((2 * (kb64) + kf) * 8 + hc0 + rm / 5) * 5 + rm % 5) * 512; \
        }                                                                      \
        gload_lds16(src + lane * 8, (char*)(BUF) + f * 1024);                  \
    }                                                                          \
} while (0)

// Wave tile 32x80: acc[hh][n], hh = 16-row half, n = 16-col frag. 20 MFMA/step.
#define COMPUTE(BUF) do {                                                      \
    const char* _bp = (const char*)(BUF);                                      \
    _Pragma("unroll")                                                          \
    for (int kf = 0; kf < 2; ++kf) {                                           \
        const bf16x8 a0 = *(const bf16x8*)(_bp + ((rs * 4 + 0 * 2) + kf) * 1024 + lane * 16); \
        const bf16x8 a1 = *(const bf16x8*)(_bp + ((rs * 4 + 1 * 2) + kf) * 1024 + lane * 16); \
        bf16x8 bb[5];                                                          \
        _Pragma("unroll")                                                      \
        for (int n = 0; n < 5; ++n)                                            \
            bb[n] = *(const bf16x8*)(_bp + 8192 + (kf * 20 + cc * 5 + n) * 1024 + lane * 16); \
        _Pragma("unroll")                                                      \
        for (int n = 0; n < 5; ++n) {                                          \
            acc[0][n] = __builtin_amdgcn_mfma_f32_16x16x32_bf16(a0, bb[n], acc[0][n], 0, 0, 0); \
            acc[1][n] = __builtin_amdgcn_mfma_f32_16x16x32_bf16(a1, bb[n], acc[1][n], 0, 0, 0); \
        }                                                                      \
    }                                                                          \
} while (0)

#define SYNCN do {                                                             \
    asm volatile("s_waitcnt vmcnt(6)" ::: "memory");                           \
    __builtin_amdgcn_sched_barrier(0);                                         \
    __builtin_amdgcn_s_barrier();                                              \
} while (0)
#define SYNC0 do {                                                             \
    asm volatile("s_waitcnt vmcnt(0)" ::: "memory");                           \
    __builtin_amdgcn_sched_barrier(0);                                         \
    __builtin_amdgcn_s_barrier();                                              \
} while (0)

// ---------------- fused: 8-wave 32x80-tile MFMA GEMM + epilogue ----------------
// grid 256 = 128 M-tiles x 2 group-halves (XCD-swizzled), 512 threads = 8 waves
// (rs 0..1 x cc 0..3). LDS read amplification halved vs r12 (114 KB/step).
__global__ __launch_bounds__(512, 2) void fused_vq_k(
    const short* __restrict__ Xb, const short* __restrict__ Wb,
    const float* __restrict__ x, const float* __restrict__ W,
    const float* __restrict__ b, const float* __restrict__ codebook,
    float* __restrict__ accf, float* __restrict__ xq) {

    __shared__ __align__(16) char bufs[3][48 * 1024];   // 147,456 B
    __shared__ float pacc[2][VSZ];
    __shared__ float cnt_f[VSZ];
    __shared__ float wmax[BM][4];
    __shared__ int   warg[BM][4];
    __shared__ float ssum[BM][4];
    __shared__ float rmax_s[BM];
    __shared__ int   rarg_s[BM];
    __shared__ int   cnt_s[BM];
    __shared__ int   list_s[BM][16];
    __shared__ int   code_s[BM];
    __shared__ int   work_s[BM];
    __shared__ int   nwork_s;

    const int tid   = threadIdx.x;
    const int lane  = tid & 63;
    const int w     = tid >> 6;       // wave 0..7
    const int l15   = lane & 15;
    const int l4    = lane >> 4;
    const int sb    = ((int)blockIdx.x & 7) * (NBLK / 8) + ((int)blockIdx.x >> 3);
    const int mt    = sb >> 1;
    const int h     = sb & 1;         // group
    const int row0  = mt * BM;
    const int rs    = w >> 2;         // row-set 0..1 (32 rows each)
    const int cc    = w & 3;          // col-chunk 0..3 (80 cols)
    const int hc0   = h * 4;
    const int nf0   = h * 20 + cc * 5;

    for (int i = tid; i < VSZ; i += 512) cnt_f[i] = 0.f;
    if (tid < BM) cnt_s[tid] = 0;
    if (tid == 0) nwork_s = 0;

    char* B0 = bufs[0];
    char* B1 = bufs[1];
    char* B2 = bufs[2];

    f32x4 acc[2][5];
#pragma unroll
    for (int hh = 0; hh < 2; ++hh)
#pragma unroll
        for (int n = 0; n < 5; ++n) acc[hh][n] = (f32x4){0.f, 0.f, 0.f, 0.f};

    STAGE(0, B0);
    STAGE(1, B1);
    __syncthreads();

#pragma unroll 1
    for (int t = 0; t < 3; ++t) {
        const int kb = 3 * t;
        STAGE(kb + 2, B2); COMPUTE(B0); SYNCN;
        STAGE(kb + 3, B0); COMPUTE(B1); SYNCN;
        STAGE(kb + 4, B1); COMPUTE(B2); SYNCN;
    }
    STAGE(11, B2); COMPUTE(B0); SYNCN;
    COMPUTE(B1); SYNC0;
    COMPUTE(B2);

    // bias (zeros in this problem, kept exact)
#pragma unroll
    for (int n = 0; n < 5; ++n) {
        const float bv = b[(nf0 + n) * 16 + l15];
#pragma unroll
        for (int hh = 0; hh < 2; ++hh)
#pragma unroll
            for (int r = 0; r < 4; ++r) acc[hh][n][r] += bv;
    }

    // E1: wave-local per-row max/argmax; rows rs*32 + hh*16 + l4*4 + r
    float m4[2][4]; int a4[2][4];
#pragma unroll
    for (int hh = 0; hh < 2; ++hh)
#pragma unroll
        for (int r = 0; r < 4; ++r) { m4[hh][r] = -3.4e38f; a4[hh][r] = 0x7fffffff; }
#pragma unroll
    for (int n = 0; n < 5; ++n) {
        const int col = (nf0 + n) * 16 + l15;
#pragma unroll
        for (int hh = 0; hh < 2; ++hh)
#pragma unroll
            for (int r = 0; r < 4; ++r) {
                const float v = acc[hh][n][r];
                if (v > m4[hh][r]) { m4[hh][r] = v; a4[hh][r] = col; }
            }
    }
#pragma unroll
    for (int off = 8; off >= 1; off >>= 1)
#pragma unroll
        for (int hh = 0; hh < 2; ++hh)
#pragma unroll
            for (int r = 0; r < 4; ++r) {
                const float om = __shfl_xor(m4[hh][r], off);
                const int   oa = __shfl_xor(a4[hh][r], off);
                if (om > m4[hh][r] || (om == m4[hh][r] && oa < a4[hh][r])) {
                    m4[hh][r] = om; a4[hh][r] = oa;
                }
            }
    if (l15 == 0)
#pragma unroll
        for (int hh = 0; hh < 2; ++hh)
#pragma unroll
            for (int r = 0; r < 4; ++r) {
                const int row = rs * 32 + hh * 16 + l4 * 4 + r;
                wmax[row][cc] = m4[hh][r];
                warg[row][cc] = a4[hh][r];
            }
    __syncthreads();

    // E2a: combine 4 col-chunks -> row max over 320
    if (tid < BM) {
        float m = -3.4e38f; int c = 0x7fffffff;
#pragma unroll
        for (int q = 0; q < 4; ++q) {
            const float mq = wmax[tid][q];
            const int   cq = warg[tid][q];
            if (mq > m || (mq == m && cq < c)) { m = mq; c = cq; }
        }
        rmax_s[tid] = m;
        rarg_s[tid] = c;
    }
    __syncthreads();

    // E2b: candidate scan + exp + denominator partials
    float rm[2][4];
#pragma unroll
    for (int hh = 0; hh < 2; ++hh)
#pragma unroll
        for (int r = 0; r < 4; ++r) rm[hh][r] = rmax_s[rs * 32 + hh * 16 + l4 * 4 + r];
    float sden[2][4] = {{0.f,0.f,0.f,0.f},{0.f,0.f,0.f,0.f}};
#pragma unroll
    for (int n = 0; n < 5; ++n) {
        const int col = (nf0 + n) * 16 + l15;
#pragma unroll
        for (int hh = 0; hh < 2; ++hh)
#pragma unroll
            for (int r = 0; r < 4; ++r) {
                const float v = acc[hh][n][r];
                if (v > rm[hh][r] - MARGIN) {
                    const int row = rs * 32 + hh * 16 + l4 * 4 + r;
                    const int idx = atomicAdd(&cnt_s[row], 1);
                    if (idx < 16) list_s[row][idx] = col;
                }
                const float e = __expf(v - rm[hh][r]);
                acc[hh][n][r] = e;
                sden[hh][r] += e;
            }
    }
#pragma unroll
    for (int off = 8; off >= 1; off >>= 1)
#pragma unroll
        for (int hh = 0; hh < 2; ++hh)
#pragma unroll
            for (int r = 0; r < 4; ++r) sden[hh][r] += __shfl_xor(sden[hh][r], off);
    if (l15 == 0)
#pragma unroll
        for (int hh = 0; hh < 2; ++hh)
#pragma unroll
            for (int r = 0; r < 4; ++r)
                ssum[rs * 32 + hh * 16 + l4 * 4 + r][cc] = sden[hh][r];
    __syncthreads();

    // E3: single-candidate fast path; multi-candidate -> worklist
    if (tid < BM) {
        if (cnt_s[tid] <= 1) {
            code_s[tid] = rarg_s[tid];
        } else {
            const int wi = atomicAdd(&nwork_s, 1);
            work_s[wi] = tid;
        }
    }

    // E5: softmax column sums -> pacc[rs][v] (plain stores, disjoint (rs,cc) slots)
    float inv[2][4];
#pragma unroll
    for (int hh = 0; hh < 2; ++hh)
#pragma unroll
        for (int r = 0; r < 4; ++r) {
            const int row = rs * 32 + hh * 16 + l4 * 4 + r;
            inv[hh][r] = 1.f / (ssum[row][0] + ssum[row][1] + ssum[row][2] + ssum[row][3]);
        }
#pragma unroll
    for (int n = 0; n < 5; ++n) {
        float pc = 0.f;
#pragma unroll
        for (int hh = 0; hh < 2; ++hh)
#pragma unroll
            for (int r = 0; r < 4; ++r) pc += acc[hh][n][r] * inv[hh][r];
        pc += __shfl_xor(pc, 16);
        pc += __shfl_xor(pc, 32);
        if (l4 == 0) pacc[rs][(nf0 + n) * 16 + l15 - h * VSZ] = pc;
    }
    __syncthreads();

    // E4: fp32-exact refinement, one wave per pending row
    const int nwork = nwork_s;
    for (int it = w; it < nwork; it += 8) {
        const int row  = work_s[it];
        const int grow = row0 + row;
        const int nc   = min(cnt_s[row], 16);
        float bestv = -3.4e38f; int bestc = 0x7fffffff;
        for (int ci = 0; ci < nc; ++ci) {
            const int col = list_s[row][ci];
            float p = 0.f;
            for (int j = lane; j < KDIM; j += 64)
                p += x[(size_t)grow * KDIM + j] * W[(size_t)col * KDIM + j];
#pragma unroll
            for (int off = 32; off >= 1; off >>= 1) p += __shfl_xor(p, off);
            p += b[col];
            if (p > bestv || (p == bestv && col < bestc)) { bestv = p; bestc = col; }
        }
        if (lane == 0) code_s[row] = bestc;
    }
    __syncthreads();

    // counts histogram in LDS
    if (tid < BM) atomicAdd(&cnt_f[code_s[tid] - h * VSZ], 1.f);

    // E7: gather xq for this block's 64 rows, its group's 128-dim half
#pragma unroll
    for (int u = 0; u < 4; ++u) {
        const int f   = tid + u * 512;      // float4 index 0..2047
        const int row = f >> 5;
        const int d4  = (f & 31) * 4;
        const int k   = code_s[row];        // global col = codebook row
        const float4 v = *(const float4*)(codebook + (size_t)k * DSZ + d4);
        *(float4*)(xq + (size_t)(row0 + row) * (GSZ * DSZ) + h * DSZ + d4) = v;
    }
    __syncthreads();

    // flush block-local sums with global atomics
    for (int i = tid; i < VSZ; i += 512) {
        atomicAdd(&accf[h * VSZ + i], cnt_f[i]);
        atomicAdd(&accf[NCOL + h * VSZ + i], pacc[0][i] + pacc[1][i]);
    }
}

// ---------------- perplexities + constant ----------------
__global__ __launch_bounds__(640) void finalize_k(const float* __restrict__ accf,
                                                  float* __restrict__ out_scalars) {
    __shared__ float se_c[GSZ], se_p[GSZ];
    const int t = threadIdx.x;
    if (t < GSZ) { se_c[t] = 0.f; se_p[t] = 0.f; }
    __syncthreads();
    const int g = t / VSZ;
    const float hp = accf[t]        * (1.f / (float)NROWS);
    const float ap = accf[NCOL + t] * (1.f / (float)NROWS);
    float tc = hp * logf(hp + 1e-7f);
    float tp = ap * logf(ap + 1e-7f);
#pragma unroll
    for (int off = 32; off >= 1; off >>= 1) {
        tc += __shfl_xor(tc, off);
        tp += __shfl_xor(tp, off);
    }
    if ((t & 63) == 0) { atomicAdd(&se_c[g], tc); atomicAdd(&se_p[g], tp); }
    __syncthreads();
    if (t == 0) {
        out_scalars[0] = (float)NCOL;
        out_scalars[1] = expf(-se_c[0]) + expf(-se_c[1]);
        out_scalars[2] = expf(-se_p[0]) + expf(-se_p[1]);
    }
}

extern "C" void kernel_launch(void* const* d_in, const int* in_sizes, int n_in,
                              void* d_out, int out_size, void* d_ws, size_t ws_size,
                              hipStream_t stream) {
    const float* x        = (const float*)d_in[0];
    const float* W        = (const float*)d_in[1];
    const float* b        = (const float*)d_in[2];
    const float* codebook = (const float*)d_in[3];
    float* out = (float*)d_out;

    short* Wb   = (short*)d_ws;                                  //   983,040 B
    short* Xb   = (short*)((char*)d_ws + 983040);                // 12,582,912 B
    float* accf = (float*)((char*)d_ws + 983040 + 12582912);     //     5,120 B

    prep_k<<<dim3(XBLKS + WBLKS), dim3(256), 0, stream>>>(x, W, Xb, Wb, accf);
    fused_vq_k<<<dim3(NBLK), dim3(512), 0, stream>>>(Xb, Wb, x, W, b, codebook,
                                                     accf, out);
    finalize_k<<<dim3(1), dim3(640), 0, stream>>>(accf, out + XQ_TOTAL);
}

// Round 15
// 50.599 us; speedup vs baseline: 5.3429x; 1.1140x over previous
//
#include <hip/hip_runtime.h>
#include <hip/hip_bf16.h>

#define NROWS 8192      // B*T
#define KDIM  768       // F_IN
#define VSZ   320       // V
#define GSZ   2         // G
#define NCOL  640       // G*V
#define DSZ   128       // D
#define BM    64        // rows per block
#define NMT   (NROWS / BM)             // 128 M-tiles
#define NBLK  (NMT * 2)                // 256 blocks (x2 group-halves) = 1/CU
#define NKB   24                       // K blocks of 32 (prep layout)
#define XQ_TOTAL (NROWS * GSZ * DSZ)   // 2097152
#define MARGIN 0.75f    // 12 sigma of bf16-dot pairwise error (sigma ~0.062)
#define XBLKS 3072                     // prep blocks for x
#define WBLKS 240                      // prep blocks for W

typedef __attribute__((ext_vector_type(8))) short bf16x8;
typedef __attribute__((ext_vector_type(4))) float f32x4;

static __device__ __forceinline__ short f2bf(float f) {
    union { __hip_bfloat16 h; short s; } u;
    u.h = __float2bfloat16(f);   // round-to-nearest-even
    return u.s;
}

static __device__ __forceinline__ void gload_lds16(const void* g, void* l) {
    __builtin_amdgcn_global_load_lds(
        (const __attribute__((address_space(1))) void*)g,
        (__attribute__((address_space(3))) void*)l, 16, 0, 0);
}

// ---------------- prep: pack x and W to frag-major bf16; zero accf ----------------
__global__ __launch_bounds__(256) void prep_k(const float* __restrict__ x,
                                              const float* __restrict__ W,
                                              short* __restrict__ Xb,
                                              short* __restrict__ Wb,
                                              float* __restrict__ accf) {
    const int bid = blockIdx.x;
    if (bid == 0) {
        for (int i = threadIdx.x; i < 2 * NCOL; i += 256) accf[i] = 0.f;
    }
    const float* src;
    short* dst;
    int id, row, k;
    if (bid < XBLKS) {
        id = bid * 256 + threadIdx.x;           // 0..786431
        const int lane = id & 63;
        const int f    = id >> 6;               // 0..12287
        const int rblk = f / NKB;
        const int kb   = f - rblk * NKB;
        row = rblk * 16 + (lane & 15);
        k   = kb * 32 + (lane >> 4) * 8;
        src = x; dst = Xb;
    } else {
        id = (bid - XBLKS) * 256 + threadIdx.x; // 0..61439
        const int lane = id & 63;
        const int f    = id >> 6;               // 0..959
        const int n    = f % 5;
        const int t2   = f / 5;
        const int hc   = t2 & 7;
        const int kb   = t2 >> 3;               // 0..23
        row = (hc * 5 + n) * 16 + (lane & 15);  // W col
        k   = kb * 32 + (lane >> 4) * 8;
        src = W; dst = Wb;
    }
    const float4 a = *(const float4*)(src + (size_t)row * KDIM + k);
    const float4 c = *(const float4*)(src + (size_t)row * KDIM + k + 4);
    bf16x8 r;
    r[0] = f2bf(a.x); r[1] = f2bf(a.y); r[2] = f2bf(a.z); r[3] = f2bf(a.w);
    r[4] = f2bf(c.x); r[5] = f2bf(c.y); r[6] = f2bf(c.z); r[7] = f2bf(c.w);
    *(bf16x8*)(dst + (size_t)id * 8) = r;
}

// Per K-step (64 k) stage: 48 frags = 8 A (f<8) + 40 B; wave w (of 16) issues
// f = w, w+16, w+32 (exactly 3 -> uniform vmcnt(3)). Frag f at byte f*1024.
#define STAGE(kb64, BUF) do {                                                  \
    _Pragma("unroll")                                                          \
    for (int j = 0; j < 3; ++j) {                                              \
        const int f = w + 16 * j;                                              \
        const short* src;                                                      \
        if (f < 8) {                                                           \
            src = Xb + ((size_t)(mt * 4 + (f >> 1)) * 24 + (2 * (kb64) + (f & 1))) * 512; \
        } else {                                                               \
            const int i = f - 8;                                               \
            const int kf = i / 20, rm = i % 20;                                \
            src = Wb + ((size_t)((2 * (kb64) + kf) * 8 + hc0 + rm / 5) * 5 + rm % 5) * 512; \
        }                                                                      \
        gload_lds16(src + lane * 8, (char*)(BUF) + f * 1024);                  \
    }                                                                          \
} while (0)

#define COMPUTE(BUF) do {                                                      \
    const char* _bp = (const char*)(BUF);                                      \
    const bf16x8 a0 = *(const bf16x8*)(_bp + (rs * 2 + 0) * 1024 + lane * 16); \
    const bf16x8 a1 = *(const bf16x8*)(_bp + (rs * 2 + 1) * 1024 + lane * 16); \
    bf16x8 b0_[5], b1_[5];                                                     \
    _Pragma("unroll")                                                          \
    for (int n = 0; n < 5; ++n) {                                              \
        b0_[n] = *(const bf16x8*)(_bp + 8192 + (cc * 5 + n) * 1024 + lane * 16);      \
        b1_[n] = *(const bf16x8*)(_bp + 8192 + (20 + cc * 5 + n) * 1024 + lane * 16); \
    }                                                                          \
    _Pragma("unroll")                                                          \
    for (int n = 0; n < 5; ++n)                                                \
        acc[n] = __builtin_amdgcn_mfma_f32_16x16x32_bf16(a0, b0_[n], acc[n], 0, 0, 0); \
    _Pragma("unroll")                                                          \
    for (int n = 0; n < 5; ++n)                                                \
        acc[n] = __builtin_amdgcn_mfma_f32_16x16x32_bf16(a1, b1_[n], acc[n], 0, 0, 0); \
} while (0)

#define SYNCN do {                                                             \
    asm volatile("s_waitcnt vmcnt(3)" ::: "memory");                           \
    __builtin_amdgcn_sched_barrier(0);                                         \
    __builtin_amdgcn_s_barrier();                                              \
} while (0)
#define SYNC0 do {                                                             \
    asm volatile("s_waitcnt vmcnt(0)" ::: "memory");                           \
    __builtin_amdgcn_sched_barrier(0);                                         \
    __builtin_amdgcn_s_barrier();                                              \
} while (0)

// ---------------- fused: 16-wave LDS-staged MFMA GEMM + epilogue (r12 structure) ----------------
// grid 256 = 128 M-tiles x 2 group-halves (XCD-swizzled); 1024 threads = 16 waves (rs x cc).
__global__ __launch_bounds__(1024, 4) void fused_vq_k(
    const short* __restrict__ Xb, const short* __restrict__ Wb,
    const float* __restrict__ x, const float* __restrict__ W,
    const float* __restrict__ b, const float* __restrict__ codebook,
    float* __restrict__ accf, float* __restrict__ xq) {

    __shared__ __align__(16) char bufs[3][48 * 1024];   // 147,456 B
    __shared__ float pacc[4][VSZ];
    __shared__ float cnt_f[VSZ];
    __shared__ float wmax[BM][4];
    __shared__ int   warg[BM][4];
    __shared__ float ssum[BM][4];
    __shared__ float rmax_s[BM];
    __shared__ int   rarg_s[BM];
    __shared__ int   cnt_s[BM];
    __shared__ int   list_s[BM][16];
    __shared__ int   code_s[BM];
    __shared__ int   work_s[BM];
    __shared__ int   nwork_s;

    const int tid   = threadIdx.x;
    const int lane  = tid & 63;
    const int w     = tid >> 6;       // wave 0..15
    const int l15   = lane & 15;
    const int l4    = lane >> 4;
    const int sb    = ((int)blockIdx.x & 7) * (NBLK / 8) + ((int)blockIdx.x >> 3);
    const int mt    = sb >> 1;
    const int h     = sb & 1;         // group
    const int row0  = mt * BM;
    const int rs    = w >> 2;         // row-set 0..3 (16 rows each)
    const int cc    = w & 3;          // col-chunk 0..3 (80 cols)
    const int rbase = rs * 16;
    const int hc0   = h * 4;
    const int nf0   = h * 20 + cc * 5;

    for (int i = tid; i < VSZ; i += 1024) cnt_f[i] = 0.f;
    if (tid < BM) cnt_s[tid] = 0;
    if (tid == 0) nwork_s = 0;

    char* B0 = bufs[0];
    char* B1 = bufs[1];
    char* B2 = bufs[2];

    f32x4 acc[5];
#pragma unroll
    for (int n = 0; n < 5; ++n) acc[n] = (f32x4){0.f, 0.f, 0.f, 0.f};

    STAGE(0, B0);
    STAGE(1, B1);
    __syncthreads();

#pragma unroll 1
    for (int t = 0; t < 3; ++t) {
        const int kb = 3 * t;
        STAGE(kb + 2, B2); COMPUTE(B0); SYNCN;
        STAGE(kb + 3, B0); COMPUTE(B1); SYNCN;
        STAGE(kb + 4, B1); COMPUTE(B2); SYNCN;
    }
    STAGE(11, B2); COMPUTE(B0); SYNCN;
    COMPUTE(B1); SYNC0;
    COMPUTE(B2);

    // bias (zeros in this problem, kept exact)
#pragma unroll
    for (int n = 0; n < 5; ++n) {
        const float bv = b[(nf0 + n) * 16 + l15];
#pragma unroll
        for (int r = 0; r < 4; ++r) acc[n][r] += bv;
    }

    // E1: wave-local per-row max/argmax (rows rbase+l4*4+r, cols (nf0+n)*16+l15)
    float m4[4]; int a4[4];
#pragma unroll
    for (int r = 0; r < 4; ++r) { m4[r] = -3.4e38f; a4[r] = 0x7fffffff; }
#pragma unroll
    for (int n = 0; n < 5; ++n) {
        const int col = (nf0 + n) * 16 + l15;
#pragma unroll
        for (int r = 0; r < 4; ++r) {
            const float v = acc[n][r];
            if (v > m4[r]) { m4[r] = v; a4[r] = col; }
        }
    }
#pragma unroll
    for (int off = 8; off >= 1; off >>= 1)
#pragma unroll
        for (int r = 0; r < 4; ++r) {
            const float om = __shfl_xor(m4[r], off);
            const int   oa = __shfl_xor(a4[r], off);
            if (om > m4[r] || (om == m4[r] && oa < a4[r])) { m4[r] = om; a4[r] = oa; }
        }
    if (l15 == 0)
#pragma unroll
        for (int r = 0; r < 4; ++r) {
            const int row = rbase + l4 * 4 + r;
            wmax[row][cc] = m4[r];
            warg[row][cc] = a4[r];
        }
    __syncthreads();

    // E2a: combine 4 col-chunks -> row max over 320
    if (tid < BM) {
        float m = -3.4e38f; int c = 0x7fffffff;
#pragma unroll
        for (int q = 0; q < 4; ++q) {
            const float mq = wmax[tid][q];
            const int   cq = warg[tid][q];
            if (mq > m || (mq == m && cq < c)) { m = mq; c = cq; }
        }
        rmax_s[tid] = m;
        rarg_s[tid] = c;
    }
    __syncthreads();

    // E2b: candidate scan + exp + denominator partials
    float rm[4];
#pragma unroll
    for (int r = 0; r < 4; ++r) rm[r] = rmax_s[rbase + l4 * 4 + r];
    float sden[4] = {0.f, 0.f, 0.f, 0.f};
#pragma unroll
    for (int n = 0; n < 5; ++n) {
        const int col = (nf0 + n) * 16 + l15;
#pragma unroll
        for (int r = 0; r < 4; ++r) {
            const float v = acc[n][r];
            if (v > rm[r] - MARGIN) {
                const int row = rbase + l4 * 4 + r;
                const int idx = atomicAdd(&cnt_s[row], 1);
                if (idx < 16) list_s[row][idx] = col;
            }
            const float e = __expf(v - rm[r]);
            acc[n][r] = e;
            sden[r] += e;
        }
    }
#pragma unroll
    for (int off = 8; off >= 1; off >>= 1)
#pragma unroll
        for (int r = 0; r < 4; ++r) sden[r] += __shfl_xor(sden[r], off);
    if (l15 == 0)
#pragma unroll
        for (int r = 0; r < 4; ++r) ssum[rbase + l4 * 4 + r][cc] = sden[r];
    __syncthreads();

    // E3: single-candidate fast path; multi-candidate -> worklist
    if (tid < BM) {
        if (cnt_s[tid] <= 1) {
            code_s[tid] = rarg_s[tid];
        } else {
            const int wi = atomicAdd(&nwork_s, 1);
            work_s[wi] = tid;
        }
    }

    // E5: softmax column sums -> pacc[rs][v] (plain stores, disjoint (rs,cc) slots)
    float inv[4];
#pragma unroll
    for (int r = 0; r < 4; ++r) {
        const int row = rbase + l4 * 4 + r;
        inv[r] = 1.f / (ssum[row][0] + ssum[row][1] + ssum[row][2] + ssum[row][3]);
    }
#pragma unroll
    for (int n = 0; n < 5; ++n) {
        float pc = 0.f;
#pragma unroll
        for (int r = 0; r < 4; ++r) pc += acc[n][r] * inv[r];
        pc += __shfl_xor(pc, 16);
        pc += __shfl_xor(pc, 32);
        if (l4 == 0) pacc[rs][(nf0 + n) * 16 + l15 - h * VSZ] = pc;
    }
    __syncthreads();

    // E4: fp32-exact refinement, one wave per pending row
    const int nwork = nwork_s;
    for (int it = w; it < nwork; it += 16) {
        const int row  = work_s[it];
        const int grow = row0 + row;
        const int nc   = min(cnt_s[row], 16);
        float bestv = -3.4e38f; int bestc = 0x7fffffff;
        for (int ci = 0; ci < nc; ++ci) {
            const int col = list_s[row][ci];
            float p = 0.f;
            for (int j = lane; j < KDIM; j += 64)
                p += x[(size_t)grow * KDIM + j] * W[(size_t)col * KDIM + j];
#pragma unroll
            for (int off = 32; off >= 1; off >>= 1) p += __shfl_xor(p, off);
            p += b[col];
            if (p > bestv || (p == bestv && col < bestc)) { bestv = p; bestc = col; }
        }
        if (lane == 0) code_s[row] = bestc;
    }
    __syncthreads();

    // counts histogram in LDS
    if (tid < BM) atomicAdd(&cnt_f[code_s[tid] - h * VSZ], 1.f);

    // E7: gather xq for this block's 64 rows, its group's 128-dim half
#pragma unroll
    for (int u = 0; u < 2; ++u) {
        const int f   = tid + u * 1024;     // float4 index 0..2047
        const int row = f >> 5;
        const int d4  = (f & 31) * 4;
        const int k   = code_s[row];        // global col = codebook row
        const float4 v = *(const float4*)(codebook + (size_t)k * DSZ + d4);
        *(float4*)(xq + (size_t)(row0 + row) * (GSZ * DSZ) + h * DSZ + d4) = v;
    }
    __syncthreads();

    // flush block-local sums with global atomics
    for (int i = tid; i < VSZ; i += 1024) {
        atomicAdd(&accf[h * VSZ + i], cnt_f[i]);
        atomicAdd(&accf[NCOL + h * VSZ + i],
                  pacc[0][i] + pacc[1][i] + pacc[2][i] + pacc[3][i]);
    }
}

// ---------------- perplexities + constant ----------------
__global__ __launch_bounds__(640) void finalize_k(const float* __restrict__ accf,
                                                  float* __restrict__ out_scalars) {
    __shared__ float se_c[GSZ], se_p[GSZ];
    const int t = threadIdx.x;
    if (t < GSZ) { se_c[t] = 0.f; se_p[t] = 0.f; }
    __syncthreads();
    const int g = t / VSZ;
    const float hp = accf[t]        * (1.f / (float)NROWS);
    const float ap = accf[NCOL + t] * (1.f / (float)NROWS);
    float tc = hp * logf(hp + 1e-7f);
    float tp = ap * logf(ap + 1e-7f);
#pragma unroll
    for (int off = 32; off >= 1; off >>= 1) {
        tc += __shfl_xor(tc, off);
        tp += __shfl_xor(tp, off);
    }
    if ((t & 63) == 0) { atomicAdd(&se_c[g], tc); atomicAdd(&se_p[g], tp); }
    __syncthreads();
    if (t == 0) {
        out_scalars[0] = (float)NCOL;
        out_scalars[1] = expf(-se_c[0]) + expf(-se_c[1]);
        out_scalars[2] = expf(-se_p[0]) + expf(-se_p[1]);
    }
}

extern "C" void kernel_launch(void* const* d_in, const int* in_sizes, int n_in,
                              void* d_out, int out_size, void* d_ws, size_t ws_size,
                              hipStream_t stream) {
    const float* x        = (const float*)d_in[0];
    const float* W        = (const float*)d_in[1];
    const float* b        = (const float*)d_in[2];
    const float* codebook = (const float*)d_in[3];
    float* out = (float*)d_out;

    short* Wb   = (short*)d_ws;                                  //   983,040 B
    short* Xb   = (short*)((char*)d_ws + 983040);                // 12,582,912 B
    float* accf = (float*)((char*)d_ws + 983040 + 12582912);     //     5,120 B

    prep_k<<<dim3(XBLKS + WBLKS), dim3(256), 0, stream>>>(x, W, Xb, Wb, accf);
    fused_vq_k<<<dim3(NBLK), dim3(1024), 0, stream>>>(Xb, Wb, x, W, b, codebook,
                                                      accf, out);
    finalize_k<<<dim3(1), dim3(640), 0, stream>>>(accf, out + XQ_TOTAL);
}